// Round 2
// baseline (692.131 us; speedup 1.0000x reference)
//
#include <hip/hip_runtime.h>
#include <math.h>

// Min-sum BP LDPC decoder, LDS-resident messages, degree-sorted checks.
// One block = one batch element; msg[] (E=32768 floats = 128 KB) lives in LDS.
//
// R3 changes vs R2 (post-mortem: swizzle useless — addresses are random after
// degree-sort permutation, conflicts unchanged at 2.84e7; WRITE_SIZE 16->54 MB
// showed scratch spills from 64-VGPR cap):
//  - VAR-MAJOR msg layout: msg[4*v+j] = message on edge rank j of var v (DV=4).
//    Var phase = one ds_read_b128 + one ds_write_b128 per var (contiguous,
//    conflict-free): 64 -> 16 LDS ops/thread/iter. Check phase gathers via
//    slot = 4*var_idx[e] + rank, random (inherent to the graph).
//  - Check slots cached in registers, packed 2-per-int (24 VGPRs, d<=12 covers
//    ~94% of Poisson(8) checks); 12<d<=16 recomputes 4 tail slots from L2-hot
//    var_idx/var_adj; d>16 (~0.4%) fully generic.
//  - __launch_bounds__(1024, 4): LDS caps occupancy at 4 waves/EU anyway, so
//    allow 128 VGPRs -> no scratch spills.
//  - Swizzle removed everywhere.

#define BLOCK 1024
#define NV    8192          // N variables
#define MC    4096          // M checks
#define NE    32768         // E edges (N * DV, DV=4)
#define VPT   (NV / BLOCK)  // 8 vars per thread
#define CPT   (MC / BLOCK)  // 4 checks per thread
#define NITER 10
#define ALPHA 0.8f
#define CLAMP 20.0f

// ---------------- setup: counting-sort checks by degree ----------------
// ws[0..MC)    : (cstart & 0xFFFF) | (deg << 16), degree-sorted
// ws[MC..2MC)  : original check index (for syndrome lookup), same order
__global__ __launch_bounds__(BLOCK)
void setup_sort(const float* __restrict__ check_mask,
                const int*   __restrict__ check_adj,
                int max_dc, int* __restrict__ ws)
{
    __shared__ int hist[64];
    __shared__ int base[64];
    const int t = threadIdx.x;
    if (t < 64) hist[t] = 0;
    __syncthreads();
    int deg[CPT], cst[CPT];
#pragma unroll
    for (int k = 0; k < CPT; ++k) {
        const int c = t + k * BLOCK;
        int d = 0;
        for (int j = 0; j < max_dc; ++j)
            d += (check_mask[(size_t)c * max_dc + j] != 0.0f) ? 1 : 0;
        deg[k] = d;
        cst[k] = check_adj[(size_t)c * max_dc];  // row start (edges sorted by check)
        atomicAdd(&hist[d & 63], 1);
    }
    __syncthreads();
    if (t == 0) {
        int s = 0;
        for (int i = 0; i < 64; ++i) { base[i] = s; s += hist[i]; }
    }
    __syncthreads();
#pragma unroll
    for (int k = 0; k < CPT; ++k) {
        const int c   = t + k * BLOCK;
        const int pos = atomicAdd(&base[deg[k] & 63], 1);
        ws[pos]      = (cst[k] & 0xFFFF) | (deg[k] << 16);
        ws[MC + pos] = c;
    }
}

// unpack packed slot j (compile-time j) from 6-int packed array
__device__ __forceinline__ int upk(const int (&ps)[6], int j) {
    return (j & 1) ? ((ps[j >> 1] >> 16) & 0xFFFF) : (ps[j >> 1] & 0xFFFF);
}

// slot of edge e from globals (L2-hot): 4*v + rank-of-e-in-var_adj[v]
__device__ __forceinline__ int slot_of(int e, const int* __restrict__ var_idx,
                                       const int* __restrict__ var_adj) {
    const int v  = var_idx[e];
    const int4 r = ((const int4*)var_adj)[v];
    const int rk = (r.y == e) ? 1 : (r.z == e) ? 2 : (r.w == e) ? 3 : 0;
    return 4 * v + rk;
}

// Check update, slots fully register-cached (d <= 12, ~94% of checks).
__device__ __forceinline__ void do_check12(float* __restrict__ msg,
                                           const int (&ps)[6],
                                           int d, float sgn, float pad)
{
    float x[12]; int sl[12];
    float min1 = pad, min2 = pad, prod = sgn;
#pragma unroll
    for (int j = 0; j < 12; ++j) {
        if (j < d) { sl[j] = upk(ps, j); x[j] = msg[sl[j]]; }
    }
#pragma unroll
    for (int j = 0; j < 12; ++j) {
        if (j < d) {
            prod = (x[j] < 0.0f) ? -prod : prod;     // sign(0)=+1 like reference
            const float a = fabsf(x[j]);
            min2 = __builtin_amdgcn_fmed3f(min1, min2, a);  // uses OLD min1
            min1 = fminf(min1, a);
        }
    }
    const float vm1 = ALPHA * min1;
    const float vm2 = ALPHA * min2;
#pragma unroll
    for (int j = 0; j < 12; ++j) {
        if (j < d) {
            const float m = (fabsf(fabsf(x[j]) - min1) < 1e-9f) ? vm2 : vm1;  // ref tie rule
            const float v = m * prod;
            msg[sl[j]] = (x[j] < 0.0f) ? -v : v;     // excl_sign = prod * sign_j
        }
    }
}

// 12 < d <= 16: first 12 slots from cache, last 4 recomputed from globals.
__device__ __forceinline__ void do_check16(float* __restrict__ msg,
                                           const int (&ps)[6], int st,
                                           int d, float sgn, float pad,
                                           const int* __restrict__ var_idx,
                                           const int* __restrict__ var_adj)
{
    float x[16]; int sl[16];
#pragma unroll
    for (int j = 0; j < 12; ++j) sl[j] = upk(ps, j);
#pragma unroll
    for (int j = 12; j < 16; ++j) {
        if (j < d) sl[j] = slot_of(st + j, var_idx, var_adj);
    }
    float min1 = pad, min2 = pad, prod = sgn;
#pragma unroll
    for (int j = 0; j < 16; ++j) {
        if (j < d) {
            x[j] = msg[sl[j]];
            prod = (x[j] < 0.0f) ? -prod : prod;
            const float a = fabsf(x[j]);
            min2 = __builtin_amdgcn_fmed3f(min1, min2, a);
            min1 = fminf(min1, a);
        }
    }
    const float vm1 = ALPHA * min1;
    const float vm2 = ALPHA * min2;
#pragma unroll
    for (int j = 0; j < 16; ++j) {
        if (j < d) {
            const float m = (fabsf(fabsf(x[j]) - min1) < 1e-9f) ? vm2 : vm1;
            const float v = m * prod;
            msg[sl[j]] = (x[j] < 0.0f) ? -v : v;
        }
    }
}

// Generic fallback for d > 16 (rare): recompute slots, re-read LDS.
__device__ void do_check_big(float* __restrict__ msg, int st,
                             int d, float sgn, float pad,
                             const int* __restrict__ var_idx,
                             const int* __restrict__ var_adj)
{
    float min1 = pad, min2 = pad, prod = sgn;
    for (int j = 0; j < d; ++j) {
        const float xx = msg[slot_of(st + j, var_idx, var_adj)];
        prod = (xx < 0.0f) ? -prod : prod;
        const float a = fabsf(xx);
        min2 = __builtin_amdgcn_fmed3f(min1, min2, a);
        min1 = fminf(min1, a);
    }
    const float vm1 = ALPHA * min1;
    const float vm2 = ALPHA * min2;
    for (int j = 0; j < d; ++j) {
        const int   s  = slot_of(st + j, var_idx, var_adj);
        const float xx = msg[s];
        const float m  = (fabsf(fabsf(xx) - min1) < 1e-9f) ? vm2 : vm1;
        const float v  = m * prod;
        msg[s] = (xx < 0.0f) ? -v : v;
    }
}

__global__ __launch_bounds__(BLOCK, 4)
void bp_decode(const float* __restrict__ syndrome,    // (B, M)
               const float* __restrict__ llr_g,       // (B, N)
               const int*   __restrict__ var_adj,     // (N, 4)
               const int*   __restrict__ var_idx,     // (E,)
               const int*   __restrict__ ws,          // sorted check info
               float* __restrict__ out,               // marginals | hard | converged
               int B)
{
    __shared__ float msg[NE];   // 128 KB, VAR-MAJOR: msg[4*v+j], in-place ctv/vtc
    __shared__ float sh_e0;     // |vtc[edge 0]| snapshot for reference's pad
    __shared__ int   mism;

    const int b = blockIdx.x;
    const int t = threadIdx.x;

    for (int e = t; e < NE; e += BLOCK) msg[e] = 0.0f;   // ctv0 = 0

    // ---- edge-0 owner (for reference's pad = |vtc[0]| + 1e6) ----
    const int  v0  = var_idx[0];
    const int4 r0  = ((const int4*)var_adj)[v0];
    const int  j0  = (r0.y == 0) ? 1 : (r0.z == 0) ? 2 : (r0.w == 0) ? 3 : 0;
    const bool own = (t == (v0 & (BLOCK - 1)));
    const int  k0  = v0 >> 10;            // v0 / BLOCK

    // ---- preload per-thread read-only data into registers ----
    float llr[VPT];
#pragma unroll
    for (int k = 0; k < VPT; ++k)
        llr[k] = llr_g[(size_t)b * NV + (t + k * BLOCK)];

    int cst[CPT], dsb[CPT];   // dsb = (deg<<1) | syndrome_bit
    int csp[CPT][6];          // packed slots (2 x 16-bit per int), ranks 0..11
#pragma unroll
    for (int k = 0; k < CPT; ++k) {
        const int i = t + k * BLOCK;
        const int w = ws[i];
        const int c = ws[MC + i];
        const int st = w & 0xFFFF;
        const int d  = w >> 16;
        cst[k] = st;
        const int sb = (syndrome[(size_t)b * MC + c] > 0.5f) ? 1 : 0;
        dsb[k] = (d << 1) | sb;
        int sl[12];
#pragma unroll
        for (int j = 0; j < 12; ++j) {
            int s = 0;
            if (j < d) s = slot_of(st + j, var_idx, var_adj);
            sl[j] = s;
        }
#pragma unroll
        for (int jj = 0; jj < 6; ++jj)
            csp[k][jj] = sl[2 * jj] | (sl[2 * jj + 1] << 16);
    }
    __syncthreads();

    for (int it = 0; it < NITER; ++it) {
        // ---- variable phase: contiguous float4 per var, in place ----
#pragma unroll
        for (int k = 0; k < VPT; ++k) {
            const int v = t + k * BLOCK;
            float4 c = *reinterpret_cast<float4*>(&msg[4 * v]);
            const float tot  = ((c.x + c.y) + c.z) + c.w;   // reference sum order
            const float base = llr[k] + tot;
            float4 o;
            o.x = __builtin_amdgcn_fmed3f(base - c.x, -CLAMP, CLAMP);
            o.y = __builtin_amdgcn_fmed3f(base - c.y, -CLAMP, CLAMP);
            o.z = __builtin_amdgcn_fmed3f(base - c.z, -CLAMP, CLAMP);
            o.w = __builtin_amdgcn_fmed3f(base - c.w, -CLAMP, CLAMP);
            *reinterpret_cast<float4*>(&msg[4 * v]) = o;
            if (own && k == k0) {
                const float vv = (j0 == 0) ? o.x : (j0 == 1) ? o.y
                               : (j0 == 2) ? o.z : o.w;
                sh_e0 = fabsf(vv) + 1.0e6f;
            }
        }
        __syncthreads();
        const float pad = sh_e0;

        // ---- check phase: gather/scatter via cached slots, in place ----
#pragma unroll
        for (int k = 0; k < CPT; ++k) {
            const int   d   = dsb[k] >> 1;
            const float sgn = (dsb[k] & 1) ? -1.0f : 1.0f;
            if (d <= 12)      do_check12(msg, csp[k], d, sgn, pad);
            else if (d <= 16) do_check16(msg, csp[k], cst[k], d, sgn, pad, var_idx, var_adj);
            else              do_check_big(msg, cst[k], d, sgn, pad, var_idx, var_adj);
        }
        __syncthreads();
    }

    // ---- finale: marginals, hard decisions, convergence ----
    float marg[VPT], hard[VPT];
#pragma unroll
    for (int k = 0; k < VPT; ++k) {
        const int v = t + k * BLOCK;
        float4 c = *reinterpret_cast<float4*>(&msg[4 * v]);
        const float tot = ((c.x + c.y) + c.z) + c.w;
        const float tl  = llr[k] + tot;
        const float mg  = 1.0f / (1.0f + expf(tl));   // sigmoid(-tl)
        marg[k] = mg;
        hard[k] = (mg > 0.5f) ? 1.0f : 0.0f;
    }
    if (t == 0) mism = 0;
    __syncthreads();   // all ctv reads done; safe to overwrite msg

    const size_t BN = (size_t)B * NV;
#pragma unroll
    for (int k = 0; k < VPT; ++k) {
        const int v = t + k * BLOCK;
        out[(size_t)b * NV + v]      = marg[k];        // output 0: marginals
        out[BN + (size_t)b * NV + v] = hard[k];        // output 1: hard_decision
        const float h = hard[k];                       // scatter hard bit to edges
        float4 hh; hh.x = h; hh.y = h; hh.z = h; hh.w = h;
        *reinterpret_cast<float4*>(&msg[4 * v]) = hh;
    }
    __syncthreads();

    // syn_hat[c] = parity over the check's edges' hard bits; converged iff == syndrome
#pragma unroll
    for (int k = 0; k < CPT; ++k) {
        const int d  = dsb[k] >> 1;
        const int sb = dsb[k] & 1;
        const int st = cst[k];
        int par = 0;
        if (d <= 12) {
#pragma unroll
            for (int j = 0; j < 12; ++j) {
                if (j < d) par ^= (msg[upk(csp[k], j)] != 0.0f) ? 1 : 0;
            }
        } else {
            for (int j = 0; j < d; ++j)
                par ^= (msg[slot_of(st + j, var_idx, var_adj)] != 0.0f) ? 1 : 0;
        }
        if (par != sb) mism = 1;   // benign race: all writers store 1
    }
    __syncthreads();
    if (t == 0) out[2 * BN + b] = mism ? 0.0f : 1.0f;  // output 2: converged
}

extern "C" void kernel_launch(void* const* d_in, const int* in_sizes, int n_in,
                              void* d_out, int out_size, void* d_ws, size_t ws_size,
                              hipStream_t stream) {
    const float* syndrome   = (const float*)d_in[0];
    const float* llr        = (const float*)d_in[1];
    const int*   var_adj    = (const int*)d_in[2];
    // d_in[3] var_adj_mask: all ones (DV=4 exact) — unused
    const int*   check_adj  = (const int*)d_in[4];
    const float* check_mask = (const float*)d_in[5];
    const int*   var_idx    = (const int*)d_in[6];
    // d_in[7] pcm_dense — unused
    float* out = (float*)d_out;
    int*   ws  = (int*)d_ws;    // needs 2*MC ints = 32 KB

    const int B      = in_sizes[0] / MC;      // 256
    const int max_dc = in_sizes[4] / MC;

    setup_sort<<<1, BLOCK, 0, stream>>>(check_mask, check_adj, max_dc, ws);
    bp_decode<<<B, BLOCK, 0, stream>>>(syndrome, llr, var_adj, var_idx, ws, out, B);
}

// Round 4
// 367.613 us; speedup vs baseline: 1.8828x; 1.8828x over previous
//
#include <hip/hip_runtime.h>
#include <math.h>

// Min-sum BP LDPC decoder, LDS-resident messages, degree-sorted checks.
// One block = one batch element; padded msg arena (~160 KB) lives in LDS.
//
// R5 = R4 theory (odd-stride padding kills check-phase bank conflicts) with
// the workspace hazard removed:
//  - R4 wrote a 128 KB pos[e] table into d_ws without checking ws_size; if
//    the harness workspace is < 160 KB that's a global OOB write -> dead
//    container (R4 "failed twice"). R5 keeps d_ws at R1's proven 32 KB.
//  - pos[e] (edge -> padded slot) is instead built PER BLOCK inside
//    bp_decode, in LDS, aliasing the not-yet-zeroed msg arena as int*:
//    scatter pb+j over each sorted check's contiguous edge range [st, st+d),
//    read the 32 var-side slots into registers, barrier, zero arena, go.
//  - Conflict theory: degree-sorted lanes read msg[st_l + j]; uniform-degree
//    runs (Poisson(8): d=8 spans ~9 waves) stride by exactly d words -> 4
//    banks for 64 lanes -> 16-way conflict (~5.7x, m136). Padded region of
//    d+1+(d&1) words makes all strides odd => coprime with 32 banks =>
//    2 lanes/bank = free. Var-phase random gather/scatter is graph-inherent.
//  - Arena 40896 words (159.9 KB): safe even for worst-case odd-degree
//    counts (expected total NE+MC+#odd ~ 38.9k). Still 1 block/CU (R1's
//    128.5 KB was also 1 block/CU) -> occupancy unchanged.
//  - amdgpu_waves_per_eu(4,4): LDS caps us at 4 waves/EU anyway; lets the
//    allocator use up to 128 VGPRs (R3 showed __launch_bounds__(1024,4)
//    does NOT raise the 64-VGPR default; it spilled 420 MB of scratch).
//  - d > 16 uses the generic fallback (register pressure stays at R1's
//    proven no-spill level).

#define BLOCK 1024
#define NV    8192          // N variables
#define MC    4096          // M checks
#define NE    32768         // E edges (N * DV, DV=4)
#define VPT   (NV / BLOCK)  // 8 vars per thread
#define CPT   (MC / BLOCK)  // 4 checks per thread
#define NITER 10
#define ALPHA 0.8f
#define CLAMP 20.0f
#define MSGW  40896         // padded arena words (159.9 KB)

// ws layout (ints), 32 KB total (same footprint R1 used successfully):
//  [0 .. MC)   : pbase(16b) | deg<<16   (degree-sorted order)
//  [MC .. 2MC) : original check index   (for syndrome + check_adj lookup)

// ---------------- setup: counting-sort + padded prefix ----------------
__global__ __launch_bounds__(BLOCK)
void setup_sort(const float* __restrict__ check_mask,
                const int*   __restrict__ check_adj,
                int max_dc, int* __restrict__ ws)
{
    __shared__ int hist[64], base[64], wsum[16];
    __shared__ int sdeg[MC];
    const int t = threadIdx.x;
    if (t < 64) hist[t] = 0;
    __syncthreads();
    int deg[CPT];
#pragma unroll
    for (int k = 0; k < CPT; ++k) {
        const int c = t + k * BLOCK;
        int d = 0;
        for (int j = 0; j < max_dc; ++j)
            d += (check_mask[(size_t)c * max_dc + j] != 0.0f) ? 1 : 0;
        deg[k] = d;
        atomicAdd(&hist[d & 63], 1);
    }
    __syncthreads();
    if (t == 0) {
        int s = 0;
        for (int i = 0; i < 64; ++i) { base[i] = s; s += hist[i]; }
    }
    __syncthreads();
#pragma unroll
    for (int k = 0; k < CPT; ++k) {
        const int pos = atomicAdd(&base[deg[k] & 63], 1);
        sdeg[pos]    = deg[k];
        ws[MC + pos] = t + k * BLOCK;   // original check index
    }
    __syncthreads();

    // ---- padded prefix sum over sorted order; thread t owns 4t..4t+3 ----
    int psz[CPT];
    int s = 0;
#pragma unroll
    for (int k = 0; k < CPT; ++k) {
        const int d = sdeg[4 * t + k];
        psz[k] = s;
        s += d + 1 + (d & 1);           // odd stride
    }
    const int lane = t & 63, wv = t >> 6;
    int run = s;
#pragma unroll
    for (int off = 1; off < 64; off <<= 1) {
        const int n = __shfl_up(run, off, 64);
        if (lane >= off) run += n;
    }
    if (lane == 63) wsum[wv] = run;
    __syncthreads();
    if (t == 0) {
        int acc = 0;
        for (int w = 0; w < 16; ++w) { const int v = wsum[w]; wsum[w] = acc; acc += v; }
    }
    __syncthreads();
    const int tb = wsum[wv] + (run - s);   // exclusive base for this thread
#pragma unroll
    for (int k = 0; k < CPT; ++k) {
        const int i = 4 * t + k;
        ws[i] = ((tb + psz[k]) & 0xFFFF) | (sdeg[i] << 16);
    }
}

// Single-pass check update, contiguous padded region, edge values in VGPRs.
template<int DMAX>
__device__ __forceinline__ void do_check(float* __restrict__ msg,
                                         int st, int d, float sgn, float pad)
{
    float x[DMAX];
    float min1 = pad, min2 = pad, prod = sgn;
#pragma unroll
    for (int j = 0; j < DMAX; ++j) {
        if (j >= d) break;
        x[j] = msg[st + j];
    }
#pragma unroll
    for (int j = 0; j < DMAX; ++j) {
        if (j >= d) break;
        prod = (x[j] < 0.0f) ? -prod : prod;            // sign(0)=+1 like ref
        const float a = fabsf(x[j]);
        min2 = __builtin_amdgcn_fmed3f(min1, min2, a);  // uses OLD min1
        min1 = fminf(min1, a);
    }
    const float vm1 = ALPHA * min1;
    const float vm2 = ALPHA * min2;
#pragma unroll
    for (int j = 0; j < DMAX; ++j) {
        if (j >= d) break;
        const float m = (fabsf(fabsf(x[j]) - min1) < 1e-9f) ? vm2 : vm1;  // ref tie rule
        const float v = m * prod;
        msg[st + j] = (x[j] < 0.0f) ? -v : v;           // excl_sign = prod * sign_j
    }
}

// Generic fallback for d > 16 (rare; re-reads LDS instead of caching).
__device__ void do_check_big(float* __restrict__ msg,
                             int st, int d, float sgn, float pad)
{
    float min1 = pad, min2 = pad, prod = sgn;
    for (int j = 0; j < d; ++j) {
        const float xx = msg[st + j];
        prod = (xx < 0.0f) ? -prod : prod;
        const float a = fabsf(xx);
        min2 = __builtin_amdgcn_fmed3f(min1, min2, a);
        min1 = fminf(min1, a);
    }
    const float vm1 = ALPHA * min1;
    const float vm2 = ALPHA * min2;
    for (int j = 0; j < d; ++j) {
        const float xx = msg[st + j];
        const float m  = (fabsf(fabsf(xx) - min1) < 1e-9f) ? vm2 : vm1;
        const float v  = m * prod;
        msg[st + j] = (xx < 0.0f) ? -v : v;
    }
}

__global__ __launch_bounds__(BLOCK) __attribute__((amdgpu_waves_per_eu(4, 4)))
void bp_decode(const float* __restrict__ syndrome,    // (B, M)
               const float* __restrict__ llr_g,       // (B, N)
               const int*   __restrict__ var_adj,     // (N, 4)
               const int*   __restrict__ var_idx,     // (E,)
               const int*   __restrict__ check_adj,   // (M, max_dc)
               int max_dc,
               const int*   __restrict__ ws,          // sorted check info (32 KB)
               float* __restrict__ out,               // marginals | hard | converged
               int B)
{
    __shared__ float msg[MSGW];  // padded arena, in-place ctv/vtc
    __shared__ float sh_e0;      // |vtc[edge 0]| snapshot for reference's pad
    __shared__ int   mism;

    const int b = blockIdx.x;
    const int t = threadIdx.x;

    // ---- load sorted-check info; build pos[e] in LDS (aliasing msg) ----
    int cst[CPT], dsb[CPT];   // padded base; (deg<<1) | syndrome_bit
    {
        int* posL = (int*)msg;
#pragma unroll
        for (int k = 0; k < CPT; ++k) {
            const int i = t + k * BLOCK;
            const int w = ws[i];
            const int c = ws[MC + i];
            const int pb = w & 0xFFFF;
            const int d  = w >> 16;
            cst[k] = pb;
            const int sb = (syndrome[(size_t)b * MC + c] > 0.5f) ? 1 : 0;
            dsb[k] = (d << 1) | sb;
            const int st = check_adj[(size_t)c * max_dc];  // first edge (contiguous)
            for (int j = 0; j < d; ++j)
                posL[st + j] = pb + j;
        }
    }
    __syncthreads();

    // ---- edge-0 owner (for reference's pad = |vtc[0]| + 1e6) ----
    const int  v0  = var_idx[0];
    const int4 r0  = ((const int4*)var_adj)[v0];
    const int  j0  = (r0.y == 0) ? 1 : (r0.z == 0) ? 2 : (r0.w == 0) ? 3 : 0;
    const bool own = (t == (v0 & (BLOCK - 1)));
    const int  k0  = v0 >> 10;            // v0 / BLOCK

    // ---- var-side padded slots + LLRs into registers ----
    int   vs[VPT][4];
    float llr[VPT];
    {
        const int* posL = (const int*)msg;
#pragma unroll
        for (int k = 0; k < VPT; ++k) {
            const int v = t + k * BLOCK;
            const int4 a = ((const int4*)var_adj)[v];   // var degree is exactly 4
            vs[k][0] = posL[a.x]; vs[k][1] = posL[a.y];
            vs[k][2] = posL[a.z]; vs[k][3] = posL[a.w];
            llr[k] = llr_g[(size_t)b * NV + v];
        }
    }
    __syncthreads();

    for (int e = t; e < MSGW; e += BLOCK) msg[e] = 0.0f;   // ctv0 = 0
    __syncthreads();

    for (int it = 0; it < NITER; ++it) {
        // ---- variable phase: msg(ctv) -> msg(vtc), in place ----
#pragma unroll
        for (int k = 0; k < VPT; ++k) {
            const float c0 = msg[vs[k][0]];
            const float c1 = msg[vs[k][1]];
            const float c2 = msg[vs[k][2]];
            const float c3 = msg[vs[k][3]];
            const float tot  = ((c0 + c1) + c2) + c3;   // reference sum order
            const float bse  = llr[k] + tot;
            const float o0 = __builtin_amdgcn_fmed3f(bse - c0, -CLAMP, CLAMP);
            const float o1 = __builtin_amdgcn_fmed3f(bse - c1, -CLAMP, CLAMP);
            const float o2 = __builtin_amdgcn_fmed3f(bse - c2, -CLAMP, CLAMP);
            const float o3 = __builtin_amdgcn_fmed3f(bse - c3, -CLAMP, CLAMP);
            msg[vs[k][0]] = o0;
            msg[vs[k][1]] = o1;
            msg[vs[k][2]] = o2;
            msg[vs[k][3]] = o3;
            if (own && k == k0) {
                const float vv = (j0 == 0) ? o0 : (j0 == 1) ? o1
                               : (j0 == 2) ? o2 : o3;
                sh_e0 = fabsf(vv) + 1.0e6f;
            }
        }
        __syncthreads();
        const float pad = sh_e0;

        // ---- check phase: contiguous padded regions, in place ----
#pragma unroll
        for (int k = 0; k < CPT; ++k) {
            const int   d   = dsb[k] >> 1;
            const float sgn = (dsb[k] & 1) ? -1.0f : 1.0f;
            const int   st  = cst[k];
            if (d <= 8)       do_check<8>(msg, st, d, sgn, pad);
            else if (d <= 12) do_check<12>(msg, st, d, sgn, pad);
            else if (d <= 16) do_check<16>(msg, st, d, sgn, pad);
            else              do_check_big(msg, st, d, sgn, pad);
        }
        __syncthreads();
    }

    // ---- finale: marginals, hard decisions, convergence ----
    float marg[VPT], hard[VPT];
#pragma unroll
    for (int k = 0; k < VPT; ++k) {
        const float c0 = msg[vs[k][0]];
        const float c1 = msg[vs[k][1]];
        const float c2 = msg[vs[k][2]];
        const float c3 = msg[vs[k][3]];
        const float tot = ((c0 + c1) + c2) + c3;
        const float tl  = llr[k] + tot;
        const float mg  = 1.0f / (1.0f + expf(tl));   // sigmoid(-tl)
        marg[k] = mg;
        hard[k] = (mg > 0.5f) ? 1.0f : 0.0f;
    }
    if (t == 0) mism = 0;
    __syncthreads();   // all ctv reads done; safe to overwrite msg

    const size_t BN = (size_t)B * NV;
#pragma unroll
    for (int k = 0; k < VPT; ++k) {
        const int v = t + k * BLOCK;
        out[(size_t)b * NV + v]      = marg[k];        // output 0: marginals
        out[BN + (size_t)b * NV + v] = hard[k];        // output 1: hard_decision
        const float h = hard[k];                       // scatter hard bit to edges
        msg[vs[k][0]] = h;
        msg[vs[k][1]] = h;
        msg[vs[k][2]] = h;
        msg[vs[k][3]] = h;
    }
    __syncthreads();

    // syn_hat[c] = parity over the check's edges' hard bits; converged iff == syndrome
#pragma unroll
    for (int k = 0; k < CPT; ++k) {
        const int d  = dsb[k] >> 1;
        const int sb = dsb[k] & 1;
        const int st = cst[k];
        int par = 0;
        for (int j = 0; j < d; ++j)
            par ^= (msg[st + j] != 0.0f) ? 1 : 0;
        if (par != sb) mism = 1;   // benign race: all writers store 1
    }
    __syncthreads();
    if (t == 0) out[2 * BN + b] = mism ? 0.0f : 1.0f;  // output 2: converged
}

extern "C" void kernel_launch(void* const* d_in, const int* in_sizes, int n_in,
                              void* d_out, int out_size, void* d_ws, size_t ws_size,
                              hipStream_t stream) {
    const float* syndrome   = (const float*)d_in[0];
    const float* llr        = (const float*)d_in[1];
    const int*   var_adj    = (const int*)d_in[2];
    // d_in[3] var_adj_mask: all ones (DV=4 exact) — unused
    const int*   check_adj  = (const int*)d_in[4];
    const float* check_mask = (const float*)d_in[5];
    const int*   var_idx    = (const int*)d_in[6];
    // d_in[7] pcm_dense — unused
    float* out = (float*)d_out;
    int*   ws  = (int*)d_ws;    // needs 2*MC ints = 32 KB (same as R1)

    const int B      = in_sizes[0] / MC;      // 256
    const int max_dc = in_sizes[4] / MC;

    setup_sort<<<1, BLOCK, 0, stream>>>(check_mask, check_adj, max_dc, ws);
    bp_decode<<<B, BLOCK, 0, stream>>>(syndrome, llr, var_adj, var_idx,
                                       check_adj, max_dc, ws, out, B);
}